// Round 1
// baseline (696.306 us; speedup 1.0000x reference)
//
#include <hip/hip_runtime.h>

// PartialSum: x[B=2048, P=1024 * L=64] fp32 -> out[B, P] = sum over each
// contiguous 64-element partition.
//
// Memory-bound: 512 MiB read + 8 MiB write -> roofline ~87 us at 6.3 TB/s.
//
// v2 (this round): previous version launched 131072 one-shot blocks with a
// single float4 load per thread (MLP=1 per thread, dependent 4-step shfl
// chain, huge block turnover) and profiled ~320 us (~27% of achievable BW).
// Restructure as a persistent grid (2048 blocks = 8 blocks/CU, exactly
// resident at 256 thr/block) + grid-stride loop with 8 independent float4
// loads in flight per thread; the 8 shfl-xor reduction chains interleave so
// DS latency overlaps. Reads stay perfectly coalesced: within one unrolled
// slot j, consecutive threads access consecutive float4s.

typedef float f4 __attribute__((ext_vector_type(4)));

__global__ __launch_bounds__(256) void PartialSum_85478439125876_kernel(
    const f4* __restrict__ x4, float* __restrict__ out, long long n4) {
    const long long stride = (long long)gridDim.x * blockDim.x;
    long long i = (long long)blockIdx.x * blockDim.x + threadIdx.x;
    const bool writer = (threadIdx.x & 15) == 0;

    // Main loop: 8 independent load->sum->reduce chains per iteration.
    for (; i + 7 * stride < n4; i += 8 * stride) {
        f4 v[8];
#pragma unroll
        for (int j = 0; j < 8; ++j) v[j] = x4[i + j * stride];

        float s[8];
#pragma unroll
        for (int j = 0; j < 8; ++j) s[j] = (v[j].x + v[j].y) + (v[j].z + v[j].w);

        // 16 lanes share one partition; butterfly across the 16-lane group.
        // Interleave the 8 chains: each step issues 8 independent ds ops.
#pragma unroll
        for (int m = 1; m < 16; m <<= 1) {
#pragma unroll
            for (int j = 0; j < 8; ++j) s[j] += __shfl_xor(s[j], m, 64);
        }

        if (writer) {
#pragma unroll
            for (int j = 0; j < 8; ++j) out[(i + j * stride) >> 4] = s[j];
        }
    }

    // Tail (not taken for the fixed 2048x65536 problem: exact divide).
    for (; i < n4; i += stride) {
        f4 v = x4[i];
        float s = (v.x + v.y) + (v.z + v.w);
#pragma unroll
        for (int m = 1; m < 16; m <<= 1) s += __shfl_xor(s, m, 64);
        if (writer) out[i >> 4] = s;
    }
}

extern "C" void kernel_launch(void* const* d_in, const int* in_sizes, int n_in,
                              void* d_out, int out_size, void* d_ws, size_t ws_size,
                              hipStream_t stream) {
    const float* x = (const float*)d_in[0];
    float* out = (float*)d_out;

    long long n = (long long)in_sizes[0];   // 2048 * 65536 elements
    long long n4 = n / 4;                   // float4 count = 33,554,432

    const int BLOCK = 256;
    // Persistent grid: 2048 blocks = 8 blocks/CU on 256 CUs, all resident.
    long long maxg = (n4 + BLOCK - 1) / BLOCK;
    int grid = (int)(maxg < 2048 ? maxg : 2048);

    PartialSum_85478439125876_kernel<<<grid, BLOCK, 0, stream>>>(
        (const f4*)x, out, n4);
}

// Round 2
// 673.507 us; speedup vs baseline: 1.0339x; 1.0339x over previous
//
#include <hip/hip_runtime.h>

// PartialSum: x[B=2048, P=1024 * L=64] fp32 -> out[B, P] = sum over each
// contiguous 64-element partition.  512 MiB read + 8 MiB write, pure
// memory-bound; roofline ~87 us at 6.3 TB/s achievable.
//
// v3: v1 (one-shot, MLP=1, compact window, ~320us) beat v2 (persistent,
// MLP=8, scattered 8MiB-apart streams, ~365us).  Combine the winners:
//  - persistent 2048-block grid (fill-kernel shape; fills hit 81% peak here)
//  - per-block CONTIGUOUS 32 KiB slab per iteration: 8 independent,
//    perfectly coalesced 1 KiB wave-loads (MLP=8, no scatter)
//  - slab index = iter*gridDim + blockIdx so the resident blocks always
//    cover one contiguous 64 MiB band (compact sliding window, like v1)
//  - 16-lane shfl_xor butterfly, 8 chains interleaved (DS ~8% of mem time)

typedef float f4 __attribute__((ext_vector_type(4)));

#define KUNR 8
#define BLOCK 256

__global__ __launch_bounds__(BLOCK) void PartialSum_85478439125876_kernel(
    const f4* __restrict__ x4, float* __restrict__ out, long long n4) {
    const int t = threadIdx.x;
    const bool writer = (t & 15) == 0;
    const int tq = t >> 4;  // 0..15 across the block's 16 writer groups

    const long long nslab = n4 / (KUNR * BLOCK);  // 16384 for this problem

    for (long long slab = blockIdx.x; slab < nslab; slab += gridDim.x) {
        const f4* base = x4 + slab * (KUNR * BLOCK);

        f4 v[KUNR];
#pragma unroll
        for (int k = 0; k < KUNR; ++k) v[k] = base[k * BLOCK + t];

        float s[KUNR];
#pragma unroll
        for (int k = 0; k < KUNR; ++k)
            s[k] = (v[k].x + v[k].y) + (v[k].z + v[k].w);

        // 16 lanes share a partition; butterfly the 8 chains interleaved.
#pragma unroll
        for (int m = 1; m < 16; m <<= 1)
#pragma unroll
            for (int k = 0; k < KUNR; ++k) s[k] += __shfl_xor(s[k], m, 64);

        if (writer) {
            // 32 KiB slab = 128 partitions; p_local = k*16 + tq.
            float* ob = out + slab * (KUNR * BLOCK / 16);
#pragma unroll
            for (int k = 0; k < KUNR; ++k) ob[k * 16 + tq] = s[k];
        }
    }

    // Tail for n4 not divisible by slab size (empty for 2048x65536).
    long long tail = nslab * (KUNR * BLOCK);
    for (long long i = tail + (long long)blockIdx.x * BLOCK + t; i < n4;
         i += (long long)gridDim.x * BLOCK) {
        f4 v = x4[i];
        float s = (v.x + v.y) + (v.z + v.w);
#pragma unroll
        for (int m = 1; m < 16; m <<= 1) s += __shfl_xor(s, m, 64);
        if (writer) out[i >> 4] = s;
    }
}

extern "C" void kernel_launch(void* const* d_in, const int* in_sizes, int n_in,
                              void* d_out, int out_size, void* d_ws, size_t ws_size,
                              hipStream_t stream) {
    const float* x = (const float*)d_in[0];
    float* out = (float*)d_out;

    long long n = (long long)in_sizes[0];   // 2048 * 65536 elements
    long long n4 = n / 4;                   // 33,554,432 float4

    const int GRID = 2048;                  // persistent: ~8 blocks/CU shape
    PartialSum_85478439125876_kernel<<<GRID, BLOCK, 0, stream>>>(
        (const f4*)x, out, n4);
}